// Round 3
// baseline (412.139 us; speedup 1.0000x reference)
//
#include <hip/hip_runtime.h>
#include <hip/hip_bf16.h>

#define NN 50000
#define EE 800000
#define SCAN_BLOCKS 196   // 196*256 = 50176 >= NN

typedef __bf16 bf16x8_t __attribute__((ext_vector_type(8)));
typedef float f32x4_t __attribute__((ext_vector_type(4)));

__device__ __forceinline__ float silu_f(float v) {
    // v * 1/(1+exp(-v)) with v_rcp_f32 (avoids the ~9-instr precise-div sequence)
    return v * __builtin_amdgcn_rcpf(1.0f + __expf(-v));
}

// ---------------- prep: x -> bf16, weights -> k-slice-major bf16, dst histogram ----------------
// WyS layout: [ks(4)][h(256)][chunk(32)] bf16 for the per-node y GEMM:
//   h<128 -> y_a (x[dst] part, We1 rows 0..127), h>=128 -> y_b (x[src] part, rows 128..255)
// We2S layout: [ks(4)][row(128)][chunk(32)] bf16
// Wn1T/Wn2T stay [n][k] for the node kernel.
__global__ void prep_kernel(const float* __restrict__ x,
                            const float* __restrict__ We1,
                            const float* __restrict__ We2,
                            const float* __restrict__ Wn1,
                            const float* __restrict__ Wn2,
                            const int* __restrict__ eidx,
                            __bf16* __restrict__ xb,
                            __bf16* __restrict__ WyS,
                            __bf16* __restrict__ We2S,
                            __bf16* __restrict__ Wn1T,
                            __bf16* __restrict__ Wn2T,
                            int* __restrict__ hist) {
    int tid = blockIdx.x * blockDim.x + threadIdx.x;
    int np = gridDim.x * blockDim.x;
    const int NX = NN * 128 / 4;
    for (int i = tid; i < NX; i += np) {
        float4 v = ((const float4*)x)[i];
        __bf16* o = xb + (size_t)i * 4;
        o[0] = (__bf16)v.x; o[1] = (__bf16)v.y; o[2] = (__bf16)v.z; o[3] = (__bf16)v.w;
    }
    for (int i = tid; i < 256 * 128; i += np) {
        int k = i >> 7, n = i & 127;
        int h = (k < 128) ? n : (128 + n);
        int k2 = k & 127;
        WyS[(k2 >> 5) * 8192 + h * 32 + (k2 & 31)] = (__bf16)We1[i];
        Wn1T[n * 256 + k] = (__bf16)Wn1[i];
    }
    for (int i = tid; i < 128 * 128; i += np) {
        int k = i >> 7, n = i & 127;
        We2S[(k >> 5) * 4096 + n * 32 + (k & 31)] = (__bf16)We2[i];
        Wn2T[n * 128 + k] = (__bf16)Wn2[i];
    }
    for (int i = tid; i < EE; i += np) {
        atomicAdd(&hist[eidx[EE + i]], 1);
    }
}

// ---------------- per-node y GEMM: y[n][0:128]=x[n]@We1a, y[n][128:256]=x[n]@We1b ----------------
// Hoists 16x of the edge-layer-1 FLOPs to per-node (50K rows instead of 1.6M gathered rows).
// No bias here (added once in the edge kernel's element-wise pass).
__global__ __launch_bounds__(256, 4)
void ygemm_kernel(const __bf16* __restrict__ xb,
                  const __bf16* __restrict__ WyS,
                  float* __restrict__ y) {
    __shared__ __align__(16) __bf16 Abf[64 * 136];
    __shared__ __align__(16) __bf16 Wy[256 * 32];

    const int t = threadIdx.x;
    const int r0 = blockIdx.x * 64;
    const int w = t >> 6;
    const int lane = t & 63;
    const int m_ = lane & 15;
    const int q = lane >> 4;

#pragma unroll
    for (int i = 0; i < 4; ++i) {
        int id = t + 256 * i;
        int rl = id >> 4, c8 = (id & 15) * 8;
        int row = r0 + rl;
        uint4 v = (row < NN) ? *(const uint4*)(xb + (long)row * 128 + c8)
                             : make_uint4(0, 0, 0, 0);
        *(uint4*)(Abf + rl * 136 + c8) = v;
    }

    f32x4_t acc[16];
#pragma unroll
    for (int ct = 0; ct < 16; ++ct) acc[ct] = (f32x4_t){0.f, 0.f, 0.f, 0.f};

    const int wrow = t >> 2;
    const int pch = (t & 3) ^ ((wrow >> 1) & 3);
    const int wofs = wrow * 32 + pch * 8;
    const int rofs = m_ * 32 + (q ^ ((m_ >> 1) & 3)) * 8;

    uint4 v0 = *(const uint4*)(WyS + t * 8);
    uint4 v1 = *(const uint4*)(WyS + 2048 + t * 8);
    uint4 v2 = *(const uint4*)(WyS + 4096 + t * 8);
    uint4 v3 = *(const uint4*)(WyS + 6144 + t * 8);
#pragma unroll
    for (int ks = 0; ks < 4; ++ks) {
        __syncthreads();                 // Abf writes (ks=0) / prior Wy reads done
        *(uint4*)(Wy + wofs) = v0;
        *(uint4*)(Wy + 64 * 32 + wofs) = v1;
        *(uint4*)(Wy + 128 * 32 + wofs) = v2;
        *(uint4*)(Wy + 192 * 32 + wofs) = v3;
        __syncthreads();                 // Wy ready
        if (ks < 3) {                    // prefetch during MFMA phase
            v0 = *(const uint4*)(WyS + (ks + 1) * 8192 + t * 8);
            v1 = *(const uint4*)(WyS + (ks + 1) * 8192 + 2048 + t * 8);
            v2 = *(const uint4*)(WyS + (ks + 1) * 8192 + 4096 + t * 8);
            v3 = *(const uint4*)(WyS + (ks + 1) * 8192 + 6144 + t * 8);
        }
        bf16x8_t a = *(const bf16x8_t*)(Abf + (w * 16 + m_) * 136 + ks * 32 + q * 8);
#pragma unroll
        for (int ct = 0; ct < 16; ++ct) {
            bf16x8_t b = *(const bf16x8_t*)(Wy + ct * (16 * 32) + rofs);
            acc[ct] = __builtin_amdgcn_mfma_f32_16x16x32_bf16(a, b, acc[ct], 0, 0, 0);
        }
    }
#pragma unroll
    for (int ct = 0; ct < 16; ++ct) {
        int c = ct * 16 + m_;
#pragma unroll
        for (int r = 0; r < 4; ++r) {
            int el = w * 16 + q * 4 + r;
            int row = r0 + el;
            if (row < NN) y[(long)row * 256 + c] = acc[ct][r];
        }
    }
}

// ---------------- counting-sort scan (3 tiny kernels) ----------------
__global__ void scan_a(const int* __restrict__ hist, int* __restrict__ bsum) {
    __shared__ int sh[256];
    int i = blockIdx.x * 256 + threadIdx.x;
    sh[threadIdx.x] = (i < NN) ? hist[i] : 0;
    __syncthreads();
    for (int s = 128; s > 0; s >>= 1) {
        if (threadIdx.x < s) sh[threadIdx.x] += sh[threadIdx.x + s];
        __syncthreads();
    }
    if (threadIdx.x == 0) bsum[blockIdx.x] = sh[0];
}

__global__ void scan_b(int* __restrict__ bsum) {
    __shared__ int sh[SCAN_BLOCKS];
    int t = threadIdx.x;
    if (t < SCAN_BLOCKS) sh[t] = bsum[t];
    __syncthreads();
    if (t == 0) {
        int acc = 0;
        for (int i = 0; i < SCAN_BLOCKS; ++i) { int v = sh[i]; sh[i] = acc; acc += v; }
    }
    __syncthreads();
    if (t < SCAN_BLOCKS) bsum[t] = sh[t];
}

__global__ void scan_c(const int* __restrict__ hist, const int* __restrict__ bsum,
                       int* __restrict__ off, int* __restrict__ cursor) {
    __shared__ int sh[256];
    int tx = threadIdx.x;
    int i = blockIdx.x * 256 + tx;
    int v = (i < NN) ? hist[i] : 0;
    sh[tx] = v;
    __syncthreads();
    for (int s = 1; s < 256; s <<= 1) {
        int add = (tx >= s) ? sh[tx - s] : 0;
        __syncthreads();
        sh[tx] += add;
        __syncthreads();
    }
    int excl = sh[tx] - v + bsum[blockIdx.x];
    if (i < NN) { off[i] = excl; cursor[i] = excl; }
    if (i == NN - 1) off[NN] = excl + v;
}

// ---------------- scatter: build sorted per-edge records (no indirection in edge kernel) ----------------
__global__ void scatter_kernel(const int* __restrict__ eidx,
                               const float* __restrict__ pos,
                               const float* __restrict__ eattr,
                               const float* __restrict__ s,
                               int* __restrict__ cursor,
                               float4* __restrict__ e_geo,
                               int2* __restrict__ e_nodes,
                               float2* __restrict__ e_gate) {
    int i = blockIdx.x * blockDim.x + threadIdx.x;
    if (i < EE) {
        int si = eidx[i];
        int di = eidx[EE + i];
        int p = atomicAdd(&cursor[di], 1);
        float dx = pos[di * 3 + 0] - pos[si * 3 + 0];
        float dy = pos[di * 3 + 1] - pos[si * 3 + 1];
        float dz = pos[di * 3 + 2] - pos[si * 3 + 2];
        e_geo[p] = make_float4(dx, dy, dz, dx * dx + dy * dy + dz * dz);
        e_nodes[p] = make_int2(si, di);
        e_gate[p] = make_float2(eattr[i], s[si]);
    }
}

// ---------------- edge kernel v7: layer-1 hoisted to per-node y; element-wise phase-1 ----------------
// block = 256 threads (4 waves), tile = 128 sorted edges.
// phase 1: A2[e][c] = silu(y_a[dst][c] + y_b[src][c] + b1 + r2*w6 + ea*w7)  (barrier-free gather)
// phase 2: layer 2 MFMA, Wt XOR-swizzled staging, prefetch issued after 2nd barrier.
// Result: lane(m_,q) holds edge w*16+m_ (+64 for tile 1), outcols ot*16+q*4+{0..3}.
__global__ __launch_bounds__(256, 3)
void edge_kernel(const float* __restrict__ y,
                 const float4* __restrict__ e_geo,
                 const int2* __restrict__ e_nodes,
                 const float2* __restrict__ e_gate,
                 const float* __restrict__ We1,   // f32, rows 256/257 (r2, edge_attr)
                 const float* __restrict__ be1,
                 const __bf16* __restrict__ We2S,
                 const float* __restrict__ be2,
                 const float* __restrict__ Wc,
                 const float* __restrict__ bc,
                 float* __restrict__ msum,
                 float* __restrict__ coordsum) {
    __shared__ __align__(16) __bf16 Wt[128 * 32];   //  8,192 B
    __shared__ __align__(16) __bf16 A2[128 * 136];  // 34,816 B; Mf (f32 64x132) aliases
    __shared__ __align__(16) float4 s_pk[128];      //  2,048 B {r2, ea, src, dst}
    __shared__ float s_sg[128], s_g[128];
    __shared__ float s_diff[128 * 3];
    __shared__ int s_dst[128];

    float* Mf = (float*)A2;

    const int t = threadIdx.x;
    const int e0 = blockIdx.x * 128;
    const int w = t >> 6;
    const int lane = t & 63;
    const int m_ = lane & 15;
    const int q = lane >> 4;

    // per-edge scalars: 3 coalesced loads, precomputed in sorted order
    if (t < 128) {
        float4 g = e_geo[e0 + t];
        int2 nd = e_nodes[e0 + t];
        float2 gt = e_gate[e0 + t];
        s_diff[t * 3 + 0] = g.x; s_diff[t * 3 + 1] = g.y; s_diff[t * 3 + 2] = g.z;
        s_pk[t] = make_float4(g.w, gt.x, __int_as_float(nd.x), __int_as_float(nd.y));
        s_sg[t] = gt.y;
        s_dst[t] = nd.y;
    }
    __syncthreads();

    const int el0 = w * 16 + m_;
    const int el1 = 64 + w * 16 + m_;

    // ---- phase 1: element-wise layer 1 (gather y, add geometry terms, SiLU -> A2) ----
    {
        const int cq = t & 31;           // f32x4 col chunk
        const int c4 = cq * 4;
        const int eb = t >> 5;           // 0..7
        float4 b1 = *(const float4*)(be1 + c4);
        float4 w6 = *(const float4*)(We1 + 256 * 128 + c4);
        float4 w7 = *(const float4*)(We1 + 257 * 128 + c4);
#pragma unroll 4
        for (int i = 0; i < 16; ++i) {
            int e = eb + i * 8;
            float4 pk4 = s_pk[e];
            float r2 = pk4.x, ea = pk4.y;
            int sn = __float_as_int(pk4.z);
            int dn = __float_as_int(pk4.w);
            float4 ya = *(const float4*)(y + (long)dn * 256 + c4);
            float4 yb = *(const float4*)(y + (long)sn * 256 + 128 + c4);
            union { __bf16 h[4]; uint2 u2; } pk;
            pk.h[0] = (__bf16)silu_f(ya.x + yb.x + b1.x + r2 * w6.x + ea * w7.x);
            pk.h[1] = (__bf16)silu_f(ya.y + yb.y + b1.y + r2 * w6.y + ea * w7.y);
            pk.h[2] = (__bf16)silu_f(ya.z + yb.z + b1.z + r2 * w6.z + ea * w7.z);
            pk.h[3] = (__bf16)silu_f(ya.w + yb.w + b1.w + r2 * w6.w + ea * w7.w);
            *(uint2*)(A2 + e * 136 + c4) = pk.u2;
        }
    }

    f32x4_t acc[2][8];
#pragma unroll
    for (int et = 0; et < 2; ++et)
#pragma unroll
        for (int ot = 0; ot < 8; ++ot) acc[et][ot] = (f32x4_t){0.f, 0.f, 0.f, 0.f};

    // staging addresses (XOR-swizzled, coalesced; see r2 notes)
    const int wrow = t >> 2;
    const int pch = (t & 3) ^ ((wrow >> 1) & 3);
    const int wofs = wrow * 32 + pch * 8;
    const int rofs = m_ * 32 + (q ^ ((m_ >> 1) & 3)) * 8;

    // ---- phase 2: layer 2, K = 128, B-operand = A2 rows (same-wave LDS) ----
    uint4 w20 = *(const uint4*)(We2S + t * 8);
    uint4 w21 = *(const uint4*)(We2S + 2048 + t * 8);
#pragma unroll
    for (int ks = 0; ks < 4; ++ks) {
        __syncthreads();                 // A2 writes (ks=0) / prior wf reads; drains prefetch
        *(uint4*)(Wt + wofs) = w20;
        *(uint4*)(Wt + 64 * 32 + wofs) = w21;
        __syncthreads();                 // Wt ready
        if (ks < 3) {                    // prefetch during MFMA phase (drains at next bar1)
            w20 = *(const uint4*)(We2S + (ks + 1) * 4096 + t * 8);
            w21 = *(const uint4*)(We2S + (ks + 1) * 4096 + 2048 + t * 8);
        }
        bf16x8_t af0 = *(const bf16x8_t*)(A2 + el0 * 136 + ks * 32 + q * 8);
        bf16x8_t af1 = *(const bf16x8_t*)(A2 + el1 * 136 + ks * 32 + q * 8);
#pragma unroll
        for (int ot = 0; ot < 8; ++ot) {
            bf16x8_t wf = *(const bf16x8_t*)(Wt + ot * (16 * 32) + rofs);
            acc[0][ot] = __builtin_amdgcn_mfma_f32_16x16x32_bf16(wf, af0, acc[0][ot], 0, 0, 0);
            acc[1][ot] = __builtin_amdgcn_mfma_f32_16x16x32_bf16(wf, af1, acc[1][ot], 0, 0, 0);
        }
    }

    // epilogue 2: + b, SiLU, * s[src]; gamma via q-lane shuffle reduce
    {
        float sg0 = s_sg[el0], sg1 = s_sg[el1];
        float gp0 = 0.f, gp1 = 0.f;
#pragma unroll
        for (int ot = 0; ot < 8; ++ot) {
            int oc = ot * 16 + q * 4;
            float4 b2 = *(const float4*)(be2 + oc);
            float4 wc = *(const float4*)(Wc + oc);
            f32x4_t v0_ = acc[0][ot], v1_ = acc[1][ot];
            v0_[0] = silu_f(v0_[0] + b2.x) * sg0; v0_[1] = silu_f(v0_[1] + b2.y) * sg0;
            v0_[2] = silu_f(v0_[2] + b2.z) * sg0; v0_[3] = silu_f(v0_[3] + b2.w) * sg0;
            v1_[0] = silu_f(v1_[0] + b2.x) * sg1; v1_[1] = silu_f(v1_[1] + b2.y) * sg1;
            v1_[2] = silu_f(v1_[2] + b2.z) * sg1; v1_[3] = silu_f(v1_[3] + b2.w) * sg1;
            acc[0][ot] = v0_; acc[1][ot] = v1_;
            gp0 += v0_[0] * wc.x + v0_[1] * wc.y + v0_[2] * wc.z + v0_[3] * wc.w;
            gp1 += v1_[0] * wc.x + v1_[1] * wc.y + v1_[2] * wc.z + v1_[3] * wc.w;
        }
        gp0 += __shfl_xor(gp0, 16); gp0 += __shfl_xor(gp0, 32);
        gp1 += __shfl_xor(gp1, 16); gp1 += __shfl_xor(gp1, 32);
        if (q == 0) {
            float b0 = bc[0];
            s_g[el0] = gp0 + b0;
            s_g[el1] = gp1 + b0;
        }
    }
    __syncthreads();   // P0: all A2 reads done (Mf aliases), s_g visible

    // coord: 24 threads, 3 axes x 8 row-chunks of 16 (atomics make chunk splits safe)
    if (t < 24) {
        int ax = t % 3, ch = t / 3;
        int base = ch * 16;
        float run = 0.f;
        int cur = s_dst[base];
        for (int r = 0; r < 16; ++r) {
            int rr = base + r;
            int d = s_dst[rr];
            if (d != cur) {
                atomicAdd(&coordsum[cur * 3 + ax], run);
                run = 0.f; cur = d;
            }
            run += s_g[rr] * s_diff[rr * 3 + ax];
        }
        atomicAdd(&coordsum[cur * 3 + ax], run);
    }

    // msum: two phases of 64 edges; all 256 threads (col x row-half), serial length 32
#pragma unroll
    for (int ph = 0; ph < 2; ++ph) {
        int lr = w * 16 + m_;
#pragma unroll
        for (int ot = 0; ot < 8; ++ot)
            *(f32x4_t*)(Mf + lr * 132 + ot * 16 + q * 4) = acc[ph][ot];
        __syncthreads();   // Mf complete
        {
            int c = t & 127;
            int half = t >> 7;               // wave-uniform (waves 0,1 -> 0; 2,3 -> 1)
            int base = ph * 64 + half * 32;
            float run = 0.f;
            int cur = s_dst[base];
            for (int r = 0; r < 32; ++r) {
                int d = s_dst[base + r];     // wave-uniform branch
                if (d != cur) {
                    atomicAdd(&msum[(long)cur * 128 + c], run);
                    run = 0.f; cur = d;
                }
                run += Mf[(half * 32 + r) * 132 + c];
            }
            atomicAdd(&msum[(long)cur * 128 + c], run);
        }
        __syncthreads();   // reduce done before Mf overwrite / exit
    }
}

// ---------------- node kernel: normalize agg + 2-layer node MLP + pos update ----------------
__global__ __launch_bounds__(256, 2)
void node_kernel(const __bf16* __restrict__ xb,
                 const float* __restrict__ msum,
                 const int* __restrict__ off,
                 const __bf16* __restrict__ Wn1T,
                 const float* __restrict__ bn1,
                 const __bf16* __restrict__ Wn2T,
                 const float* __restrict__ bn2,
                 const float* __restrict__ pos,
                 const float* __restrict__ csum,
                 float* __restrict__ xout,
                 float* __restrict__ pout) {
    __shared__ __align__(16) __bf16 Abf[64 * 264];
    __shared__ __align__(16) __bf16 Wt[128 * 56];
    __shared__ __align__(16) __bf16 A2[64 * 136];

    const int t = threadIdx.x;
    const int r0 = blockIdx.x * 64;
    const int w = t >> 6;
    const int lane = t & 63;
    const int m_ = lane & 15;
    const int q = lane >> 4;

    // pos update for this block's 64 nodes (independent of the MLP)
    if (t < 192) {
        int node = r0 + t / 3;
        if (node < NN) {
            int dg = off[node + 1] - off[node];
            float inv = 1.f / (float)(dg < 1 ? 1 : dg);
            int fl = node * 3 + t % 3;
            pout[fl] = pos[fl] + csum[fl] * inv;
        }
    }

    for (int i = 0; i < 8; ++i) {
        int id = t + 256 * i;
        int rl = id >> 5, ch = id & 31;
        int row = r0 + rl;
        int c8 = (ch & 15) * 8;
        union { __bf16 h[8]; uint4 u; } pk;
        if (row < NN) {
            if (ch < 16) {
                pk.u = *(const uint4*)(xb + (long)row * 128 + c8);
            } else {
                const float* mp = msum + (long)row * 128 + c8;
                int dg = off[row + 1] - off[row];
                float inv = 1.f / (float)(dg < 1 ? 1 : dg);
#pragma unroll
                for (int j = 0; j < 8; ++j) pk.h[j] = (__bf16)(mp[j] * inv);
            }
        } else {
            pk.u = make_uint4(0, 0, 0, 0);
        }
        *(uint4*)(Abf + rl * 264 + ((ch < 16) ? 0 : 128) + c8) = pk.u;
    }
    __syncthreads();

    f32x4_t acc[8];
#pragma unroll
    for (int ct = 0; ct < 8; ++ct) acc[ct] = (f32x4_t){0.f, 0.f, 0.f, 0.f};

    for (int ks = 0; ks < 8; ++ks) {
#pragma unroll
        for (int i = 0; i < 2; ++i) {
            int c = t + 256 * i;
            int n = c >> 2, ko = (c & 3) * 8;
            uint4 v = *(const uint4*)(Wn1T + n * 256 + ks * 32 + ko);
            *(uint4*)(Wt + n * 56 + ko) = v;
        }
        __syncthreads();
        bf16x8_t a = *(const bf16x8_t*)(Abf + (w * 16 + m_) * 264 + ks * 32 + q * 8);
#pragma unroll
        for (int ct = 0; ct < 8; ++ct) {
            bf16x8_t b = *(const bf16x8_t*)(Wt + (ct * 16 + m_) * 56 + q * 8);
            acc[ct] = __builtin_amdgcn_mfma_f32_16x16x32_bf16(a, b, acc[ct], 0, 0, 0);
        }
        __syncthreads();
    }
#pragma unroll
    for (int ct = 0; ct < 8; ++ct) {
        int c = ct * 16 + m_;
        float b1 = bn1[c];
#pragma unroll
        for (int r = 0; r < 4; ++r) {
            int el = w * 16 + q * 4 + r;
            float v = acc[ct][r] + b1;
            A2[el * 136 + c] = (__bf16)silu_f(v);
        }
    }
    __syncthreads();

#pragma unroll
    for (int ct = 0; ct < 8; ++ct) acc[ct] = (f32x4_t){0.f, 0.f, 0.f, 0.f};

    for (int ks = 0; ks < 4; ++ks) {
#pragma unroll
        for (int i = 0; i < 2; ++i) {
            int c = t + 256 * i;
            int n = c >> 2, ko = (c & 3) * 8;
            uint4 v = *(const uint4*)(Wn2T + n * 128 + ks * 32 + ko);
            *(uint4*)(Wt + n * 56 + ko) = v;
        }
        __syncthreads();
        bf16x8_t a = *(const bf16x8_t*)(A2 + (w * 16 + m_) * 136 + ks * 32 + q * 8);
#pragma unroll
        for (int ct = 0; ct < 8; ++ct) {
            bf16x8_t b = *(const bf16x8_t*)(Wt + (ct * 16 + m_) * 56 + q * 8);
            acc[ct] = __builtin_amdgcn_mfma_f32_16x16x32_bf16(a, b, acc[ct], 0, 0, 0);
        }
        __syncthreads();
    }
#pragma unroll
    for (int ct = 0; ct < 8; ++ct) {
        int c = ct * 16 + m_;
        float b2 = bn2[c];
#pragma unroll
        for (int r = 0; r < 4; ++r) {
            int el = w * 16 + q * 4 + r;
            int row = r0 + el;
            if (row < NN) xout[(long)row * 128 + c] = acc[ct][r] + b2;
        }
    }
}

extern "C" void kernel_launch(void* const* d_in, const int* in_sizes, int n_in,
                              void* d_out, int out_size, void* d_ws, size_t ws_size,
                              hipStream_t stream) {
    const float* x     = (const float*)d_in[0];
    const float* pos   = (const float*)d_in[1];
    const int*   eidx  = (const int*)d_in[2];
    const float* eattr = (const float*)d_in[3];
    const float* s     = (const float*)d_in[4];
    const float* We1   = (const float*)d_in[5];
    const float* be1   = (const float*)d_in[6];
    const float* We2   = (const float*)d_in[7];
    const float* be2   = (const float*)d_in[8];
    const float* Wn1   = (const float*)d_in[9];
    const float* bn1   = (const float*)d_in[10];
    const float* Wn2   = (const float*)d_in[11];
    const float* bn2   = (const float*)d_in[12];
    const float* Wc    = (const float*)d_in[13];
    const float* bc    = (const float*)d_in[14];

    char* ws = (char*)d_ws;
    __bf16* xb     = (__bf16*)(ws);                 // 12,800,000
    __bf16* WyS    = (__bf16*)(ws + 12800000);      //     65,536
    __bf16* We2S   = (__bf16*)(ws + 12865536);      //     32,768
    __bf16* Wn1T   = (__bf16*)(ws + 12898304);      //     65,536
    __bf16* Wn2T   = (__bf16*)(ws + 12963840);      //     32,768
    float*  msum   = (float*)(ws + 12996608);       // 25,600,000
    float*  csum   = (float*)(ws + 38596608);       //    600,000
    int*    hist   = (int*)(ws + 39196608);         //    200,000
    int*    off    = (int*)(ws + 39396608);         //    200,064
    int*    cursor = (int*)(ws + 39596672);         //    200,064
    float4* e_geo  = (float4*)(ws + 39796736);      // 12,800,000 (16B aligned)
    int2*   e_nodes= (int2*)(ws + 52596736);        //  6,400,000
    float2* e_gate = (float2*)(ws + 58996736);      //  6,400,000
    int*    bsum   = (int*)(ws + 65396736);         //      1,024
    float*  y      = (float*)(ws + 65397760);       // 51,200,000 (end 116,597,760)

    float* xout = (float*)d_out;
    float* pout = xout + (size_t)NN * 128;

    // zero msum + csum + hist (contiguous, 26.4 MB)
    hipMemsetAsync(ws + 12996608, 0, 26400000, stream);
    prep_kernel<<<1024, 256, 0, stream>>>(x, We1, We2, Wn1, Wn2, eidx,
                                          xb, WyS, We2S, Wn1T, Wn2T, hist);
    ygemm_kernel<<<(NN + 63) / 64, 256, 0, stream>>>(xb, WyS, y);
    scan_a<<<SCAN_BLOCKS, 256, 0, stream>>>(hist, bsum);
    scan_b<<<1, 256, 0, stream>>>(bsum);
    scan_c<<<SCAN_BLOCKS, 256, 0, stream>>>(hist, bsum, off, cursor);
    scatter_kernel<<<(EE + 255) / 256, 256, 0, stream>>>(eidx, pos, eattr, s, cursor,
                                                         e_geo, e_nodes, e_gate);
    edge_kernel<<<EE / 128, 256, 0, stream>>>(y, e_geo, e_nodes, e_gate,
                                              We1, be1, We2S, be2, Wc, bc,
                                              msum, csum);
    node_kernel<<<(NN + 63) / 64, 256, 0, stream>>>(xb, msum, off, Wn1T, bn1, Wn2T, bn2,
                                                    pos, csum, xout, pout);
}

// Round 4
// 371.757 us; speedup vs baseline: 1.1086x; 1.1086x over previous
//
#include <hip/hip_runtime.h>
#include <hip/hip_bf16.h>

#define NN 50000
#define EE 800000
#define SCAN_BLOCKS 196   // 196*256 = 50176 >= NN

typedef __bf16 bf16x8_t __attribute__((ext_vector_type(8)));
typedef float f32x4_t __attribute__((ext_vector_type(4)));

__device__ __forceinline__ float silu_f(float v) {
    // v * 1/(1+exp(-v)) with v_rcp_f32 (avoids the ~9-instr precise-div sequence)
    return v * __builtin_amdgcn_rcpf(1.0f + __expf(-v));
}

__device__ __forceinline__ float bf_lo(unsigned u) { return __uint_as_float(u << 16); }
__device__ __forceinline__ float bf_hi(unsigned u) { return __uint_as_float(u & 0xffff0000u); }

// ---------------- prep: x -> bf16, weights -> k-slice-major bf16, dst histogram ----------------
// WyS layout: [ks(4)][h(256)][chunk(32)] bf16 for the per-node y GEMM:
//   h<128 -> y_a (x[dst] part, We1 rows 0..127), h>=128 -> y_b (x[src] part, rows 128..255)
// We2S layout: [ks(4)][row(128)][chunk(32)] bf16
// Wn1T/Wn2T stay [n][k] for the node kernel.
__global__ void prep_kernel(const float* __restrict__ x,
                            const float* __restrict__ We1,
                            const float* __restrict__ We2,
                            const float* __restrict__ Wn1,
                            const float* __restrict__ Wn2,
                            const int* __restrict__ eidx,
                            __bf16* __restrict__ xb,
                            __bf16* __restrict__ WyS,
                            __bf16* __restrict__ We2S,
                            __bf16* __restrict__ Wn1T,
                            __bf16* __restrict__ Wn2T,
                            int* __restrict__ hist) {
    int tid = blockIdx.x * blockDim.x + threadIdx.x;
    int np = gridDim.x * blockDim.x;
    const int NX = NN * 128 / 4;
    for (int i = tid; i < NX; i += np) {
        float4 v = ((const float4*)x)[i];
        __bf16* o = xb + (size_t)i * 4;
        o[0] = (__bf16)v.x; o[1] = (__bf16)v.y; o[2] = (__bf16)v.z; o[3] = (__bf16)v.w;
    }
    for (int i = tid; i < 256 * 128; i += np) {
        int k = i >> 7, n = i & 127;
        int h = (k < 128) ? n : (128 + n);
        int k2 = k & 127;
        WyS[(k2 >> 5) * 8192 + h * 32 + (k2 & 31)] = (__bf16)We1[i];
        Wn1T[n * 256 + k] = (__bf16)Wn1[i];
    }
    for (int i = tid; i < 128 * 128; i += np) {
        int k = i >> 7, n = i & 127;
        We2S[(k >> 5) * 4096 + n * 32 + (k & 31)] = (__bf16)We2[i];
        Wn2T[n * 128 + k] = (__bf16)Wn2[i];
    }
    for (int i = tid; i < EE; i += np) {
        atomicAdd(&hist[eidx[EE + i]], 1);
    }
}

// ---------------- per-node y GEMM v2: operand-swapped, bf16 split output, no x staging ----------------
// ya[n][c] = (x[n] @ We1a)[c], yb[n][c] = (x[n] @ We1b)[c], bf16 (bias added in edge phase-1).
// mfma(wf, xf): B-col = node (m_), A-row = out-neuron (ot*16+m_ in frag space);
// C: acc[ot][r] = y[node m_][outcol ot*16 + q*4 + r] -> 4 consecutive cols per lane -> 8B stores.
__global__ __launch_bounds__(256, 3)
void ygemm_kernel(const __bf16* __restrict__ xb,
                  const __bf16* __restrict__ WyS,
                  __bf16* __restrict__ ya,
                  __bf16* __restrict__ yb) {
    __shared__ __align__(16) __bf16 Wy[256 * 32];   // 16 KB, XOR-swizzled chunks

    const int t = threadIdx.x;
    const int r0 = blockIdx.x * 64;
    const int w = t >> 6;
    const int lane = t & 63;
    const int m_ = lane & 15;
    const int q = lane >> 4;

    const int node = r0 + w * 16 + m_;
    const long nrow = (long)(node < NN ? node : NN - 1) * 128;

    f32x4_t acc[16];
#pragma unroll
    for (int ot = 0; ot < 16; ++ot) acc[ot] = (f32x4_t){0.f, 0.f, 0.f, 0.f};

    const int wrow = t >> 2;                        // 0..63
    const int pch = (t & 3) ^ ((wrow >> 1) & 3);
    const int wofs = wrow * 32 + pch * 8;
    const int rofs = m_ * 32 + (q ^ ((m_ >> 1) & 3)) * 8;

    bf16x8_t xf = *(const bf16x8_t*)(xb + nrow + q * 8);
    uint4 v0 = *(const uint4*)(WyS + t * 8);
    uint4 v1 = *(const uint4*)(WyS + 2048 + t * 8);
    uint4 v2 = *(const uint4*)(WyS + 4096 + t * 8);
    uint4 v3 = *(const uint4*)(WyS + 6144 + t * 8);
#pragma unroll
    for (int ks = 0; ks < 4; ++ks) {
        __syncthreads();                 // prior Wy reads done
        *(uint4*)(Wy + wofs) = v0;
        *(uint4*)(Wy + 64 * 32 + wofs) = v1;
        *(uint4*)(Wy + 128 * 32 + wofs) = v2;
        *(uint4*)(Wy + 192 * 32 + wofs) = v3;
        __syncthreads();                 // Wy ready
        bf16x8_t nxf;
        if (ks < 3) {                    // prefetch during MFMA phase
            v0 = *(const uint4*)(WyS + (ks + 1) * 8192 + t * 8);
            v1 = *(const uint4*)(WyS + (ks + 1) * 8192 + 2048 + t * 8);
            v2 = *(const uint4*)(WyS + (ks + 1) * 8192 + 4096 + t * 8);
            v3 = *(const uint4*)(WyS + (ks + 1) * 8192 + 6144 + t * 8);
            nxf = *(const bf16x8_t*)(xb + nrow + (ks + 1) * 32 + q * 8);
        }
#pragma unroll
        for (int ot = 0; ot < 16; ++ot) {
            bf16x8_t wf = *(const bf16x8_t*)(Wy + ot * (16 * 32) + rofs);
            acc[ot] = __builtin_amdgcn_mfma_f32_16x16x32_bf16(wf, xf, acc[ot], 0, 0, 0);
        }
        if (ks < 3) xf = nxf;
    }

    if (node < NN) {
#pragma unroll
        for (int ot = 0; ot < 16; ++ot) {
            union { __bf16 h[4]; uint2 u; } pk;
            pk.h[0] = (__bf16)acc[ot][0];
            pk.h[1] = (__bf16)acc[ot][1];
            pk.h[2] = (__bf16)acc[ot][2];
            pk.h[3] = (__bf16)acc[ot][3];
            int col = (ot & 7) * 16 + q * 4;
            __bf16* dst = (ot < 8 ? ya : yb) + (long)node * 128 + col;
            *(uint2*)dst = pk.u;
        }
    }
}

// ---------------- counting-sort scan (3 tiny kernels) ----------------
__global__ void scan_a(const int* __restrict__ hist, int* __restrict__ bsum) {
    __shared__ int sh[256];
    int i = blockIdx.x * 256 + threadIdx.x;
    sh[threadIdx.x] = (i < NN) ? hist[i] : 0;
    __syncthreads();
    for (int s = 128; s > 0; s >>= 1) {
        if (threadIdx.x < s) sh[threadIdx.x] += sh[threadIdx.x + s];
        __syncthreads();
    }
    if (threadIdx.x == 0) bsum[blockIdx.x] = sh[0];
}

__global__ void scan_b(int* __restrict__ bsum) {
    __shared__ int sh[SCAN_BLOCKS];
    int t = threadIdx.x;
    if (t < SCAN_BLOCKS) sh[t] = bsum[t];
    __syncthreads();
    if (t == 0) {
        int acc = 0;
        for (int i = 0; i < SCAN_BLOCKS; ++i) { int v = sh[i]; sh[i] = acc; acc += v; }
    }
    __syncthreads();
    if (t < SCAN_BLOCKS) bsum[t] = sh[t];
}

__global__ void scan_c(const int* __restrict__ hist, const int* __restrict__ bsum,
                       int* __restrict__ off, int* __restrict__ cursor) {
    __shared__ int sh[256];
    int tx = threadIdx.x;
    int i = blockIdx.x * 256 + tx;
    int v = (i < NN) ? hist[i] : 0;
    sh[tx] = v;
    __syncthreads();
    for (int s = 1; s < 256; s <<= 1) {
        int add = (tx >= s) ? sh[tx - s] : 0;
        __syncthreads();
        sh[tx] += add;
        __syncthreads();
    }
    int excl = sh[tx] - v + bsum[blockIdx.x];
    if (i < NN) { off[i] = excl; cursor[i] = excl; }
    if (i == NN - 1) off[NN] = excl + v;
}

// ---------------- scatter: build sorted per-edge records (no indirection in edge kernel) ----------------
__global__ void scatter_kernel(const int* __restrict__ eidx,
                               const float* __restrict__ pos,
                               const float* __restrict__ eattr,
                               const float* __restrict__ s,
                               int* __restrict__ cursor,
                               float4* __restrict__ e_geo,
                               int2* __restrict__ e_nodes,
                               float2* __restrict__ e_gate) {
    int i = blockIdx.x * blockDim.x + threadIdx.x;
    if (i < EE) {
        int si = eidx[i];
        int di = eidx[EE + i];
        int p = atomicAdd(&cursor[di], 1);
        float dx = pos[di * 3 + 0] - pos[si * 3 + 0];
        float dy = pos[di * 3 + 1] - pos[si * 3 + 1];
        float dz = pos[di * 3 + 2] - pos[si * 3 + 2];
        e_geo[p] = make_float4(dx, dy, dz, dx * dx + dy * dy + dz * dz);
        e_nodes[p] = make_int2(si, di);
        e_gate[p] = make_float2(eattr[i], s[si]);
    }
}

// ---------------- edge kernel v8: bf16 split-y gather phase-1; layer-2 MFMA phase-2 ----------------
// block = 256 threads (4 waves), tile = 128 sorted edges.
// phase 1: A2[e][c] = silu(ya[dst][c] + yb[src][c] + b1 + r2*w6 + ea*w7)  (barrier-free gather;
//          each edge reads one full 256B row of ya and of yb -> 100% line utilization)
// phase 2: layer 2 MFMA, Wt XOR-swizzled staging, prefetch issued after 2nd barrier.
// Result: lane(m_,q) holds edge w*16+m_ (+64 for tile 1), outcols ot*16+q*4+{0..3}.
__global__ __launch_bounds__(256, 3)
void edge_kernel(const __bf16* __restrict__ ya,
                 const __bf16* __restrict__ yb,
                 const float4* __restrict__ e_geo,
                 const int2* __restrict__ e_nodes,
                 const float2* __restrict__ e_gate,
                 const float* __restrict__ We1,   // f32, rows 256/257 (r2, edge_attr)
                 const float* __restrict__ be1,
                 const __bf16* __restrict__ We2S,
                 const float* __restrict__ be2,
                 const float* __restrict__ Wc,
                 const float* __restrict__ bc,
                 float* __restrict__ msum,
                 float* __restrict__ coordsum) {
    __shared__ __align__(16) __bf16 Wt[128 * 32];   //  8,192 B
    __shared__ __align__(16) __bf16 A2[128 * 136];  // 34,816 B; Mf (f32 64x132) aliases
    __shared__ __align__(16) float4 s_pk[128];      //  2,048 B {r2, ea, src, dst}
    __shared__ float s_sg[128], s_g[128];
    __shared__ float s_diff[128 * 3];
    __shared__ int s_dst[128];

    float* Mf = (float*)A2;

    const int t = threadIdx.x;
    const int e0 = blockIdx.x * 128;
    const int w = t >> 6;
    const int lane = t & 63;
    const int m_ = lane & 15;
    const int q = lane >> 4;

    // per-edge scalars: 3 coalesced loads, precomputed in sorted order
    if (t < 128) {
        float4 g = e_geo[e0 + t];
        int2 nd = e_nodes[e0 + t];
        float2 gt = e_gate[e0 + t];
        s_diff[t * 3 + 0] = g.x; s_diff[t * 3 + 1] = g.y; s_diff[t * 3 + 2] = g.z;
        s_pk[t] = make_float4(g.w, gt.x, __int_as_float(nd.x), __int_as_float(nd.y));
        s_sg[t] = gt.y;
        s_dst[t] = nd.y;
    }
    __syncthreads();

    const int el0 = w * 16 + m_;
    const int el1 = 64 + w * 16 + m_;

    // ---- phase 1: element-wise layer 1 (gather bf16 ya/yb, add geometry terms, SiLU -> A2) ----
    {
        const int c8 = (t & 15) * 8;     // 8-col chunk
        const int eb = t >> 4;           // 0..15
        float4 b1a = *(const float4*)(be1 + c8);
        float4 b1b = *(const float4*)(be1 + c8 + 4);
        float4 w6a = *(const float4*)(We1 + 256 * 128 + c8);
        float4 w6b = *(const float4*)(We1 + 256 * 128 + c8 + 4);
        float4 w7a = *(const float4*)(We1 + 257 * 128 + c8);
        float4 w7b = *(const float4*)(We1 + 257 * 128 + c8 + 4);
#pragma unroll 2
        for (int i = 0; i < 8; ++i) {
            int e = eb + i * 16;
            float4 pk4 = s_pk[e];
            float r2 = pk4.x, ea = pk4.y;
            int sn = __float_as_int(pk4.z);
            int dn = __float_as_int(pk4.w);
            uint4 av = *(const uint4*)(ya + (long)dn * 128 + c8);
            uint4 bv = *(const uint4*)(yb + (long)sn * 128 + c8);
            union { __bf16 h[8]; uint4 u; } pk;
            pk.h[0] = (__bf16)silu_f(bf_lo(av.x) + bf_lo(bv.x) + b1a.x + r2 * w6a.x + ea * w7a.x);
            pk.h[1] = (__bf16)silu_f(bf_hi(av.x) + bf_hi(bv.x) + b1a.y + r2 * w6a.y + ea * w7a.y);
            pk.h[2] = (__bf16)silu_f(bf_lo(av.y) + bf_lo(bv.y) + b1a.z + r2 * w6a.z + ea * w7a.z);
            pk.h[3] = (__bf16)silu_f(bf_hi(av.y) + bf_hi(bv.y) + b1a.w + r2 * w6a.w + ea * w7a.w);
            pk.h[4] = (__bf16)silu_f(bf_lo(av.z) + bf_lo(bv.z) + b1b.x + r2 * w6b.x + ea * w7b.x);
            pk.h[5] = (__bf16)silu_f(bf_hi(av.z) + bf_hi(bv.z) + b1b.y + r2 * w6b.y + ea * w7b.y);
            pk.h[6] = (__bf16)silu_f(bf_lo(av.w) + bf_lo(bv.w) + b1b.z + r2 * w6b.z + ea * w7b.z);
            pk.h[7] = (__bf16)silu_f(bf_hi(av.w) + bf_hi(bv.w) + b1b.w + r2 * w6b.w + ea * w7b.w);
            *(uint4*)(A2 + e * 136 + c8) = pk.u;
        }
    }

    f32x4_t acc[2][8];
#pragma unroll
    for (int et = 0; et < 2; ++et)
#pragma unroll
        for (int ot = 0; ot < 8; ++ot) acc[et][ot] = (f32x4_t){0.f, 0.f, 0.f, 0.f};

    // staging addresses (XOR-swizzled, coalesced; see r2 notes)
    const int wrow = t >> 2;
    const int pch = (t & 3) ^ ((wrow >> 1) & 3);
    const int wofs = wrow * 32 + pch * 8;
    const int rofs = m_ * 32 + (q ^ ((m_ >> 1) & 3)) * 8;

    // ---- phase 2: layer 2, K = 128, B-operand = A2 rows (same-wave LDS) ----
    uint4 w20 = *(const uint4*)(We2S + t * 8);
    uint4 w21 = *(const uint4*)(We2S + 2048 + t * 8);
#pragma unroll
    for (int ks = 0; ks < 4; ++ks) {
        __syncthreads();                 // A2 writes (ks=0) / prior wf reads; drains prefetch
        *(uint4*)(Wt + wofs) = w20;
        *(uint4*)(Wt + 64 * 32 + wofs) = w21;
        __syncthreads();                 // Wt ready
        if (ks < 3) {                    // prefetch during MFMA phase (drains at next bar1)
            w20 = *(const uint4*)(We2S + (ks + 1) * 4096 + t * 8);
            w21 = *(const uint4*)(We2S + (ks + 1) * 4096 + 2048 + t * 8);
        }
        bf16x8_t af0 = *(const bf16x8_t*)(A2 + el0 * 136 + ks * 32 + q * 8);
        bf16x8_t af1 = *(const bf16x8_t*)(A2 + el1 * 136 + ks * 32 + q * 8);
#pragma unroll
        for (int ot = 0; ot < 8; ++ot) {
            bf16x8_t wf = *(const bf16x8_t*)(Wt + ot * (16 * 32) + rofs);
            acc[0][ot] = __builtin_amdgcn_mfma_f32_16x16x32_bf16(wf, af0, acc[0][ot], 0, 0, 0);
            acc[1][ot] = __builtin_amdgcn_mfma_f32_16x16x32_bf16(wf, af1, acc[1][ot], 0, 0, 0);
        }
    }

    // epilogue 2: + b, SiLU, * s[src]; gamma via q-lane shuffle reduce
    {
        float sg0 = s_sg[el0], sg1 = s_sg[el1];
        float gp0 = 0.f, gp1 = 0.f;
#pragma unroll
        for (int ot = 0; ot < 8; ++ot) {
            int oc = ot * 16 + q * 4;
            float4 b2 = *(const float4*)(be2 + oc);
            float4 wc = *(const float4*)(Wc + oc);
            f32x4_t v0_ = acc[0][ot], v1_ = acc[1][ot];
            v0_[0] = silu_f(v0_[0] + b2.x) * sg0; v0_[1] = silu_f(v0_[1] + b2.y) * sg0;
            v0_[2] = silu_f(v0_[2] + b2.z) * sg0; v0_[3] = silu_f(v0_[3] + b2.w) * sg0;
            v1_[0] = silu_f(v1_[0] + b2.x) * sg1; v1_[1] = silu_f(v1_[1] + b2.y) * sg1;
            v1_[2] = silu_f(v1_[2] + b2.z) * sg1; v1_[3] = silu_f(v1_[3] + b2.w) * sg1;
            acc[0][ot] = v0_; acc[1][ot] = v1_;
            gp0 += v0_[0] * wc.x + v0_[1] * wc.y + v0_[2] * wc.z + v0_[3] * wc.w;
            gp1 += v1_[0] * wc.x + v1_[1] * wc.y + v1_[2] * wc.z + v1_[3] * wc.w;
        }
        gp0 += __shfl_xor(gp0, 16); gp0 += __shfl_xor(gp0, 32);
        gp1 += __shfl_xor(gp1, 16); gp1 += __shfl_xor(gp1, 32);
        if (q == 0) {
            float b0 = bc[0];
            s_g[el0] = gp0 + b0;
            s_g[el1] = gp1 + b0;
        }
    }
    __syncthreads();   // P0: all A2 reads done (Mf aliases), s_g visible

    // coord: 24 threads, 3 axes x 8 row-chunks of 16 (atomics make chunk splits safe)
    if (t < 24) {
        int ax = t % 3, ch = t / 3;
        int base = ch * 16;
        float run = 0.f;
        int cur = s_dst[base];
        for (int r = 0; r < 16; ++r) {
            int rr = base + r;
            int d = s_dst[rr];
            if (d != cur) {
                atomicAdd(&coordsum[cur * 3 + ax], run);
                run = 0.f; cur = d;
            }
            run += s_g[rr] * s_diff[rr * 3 + ax];
        }
        atomicAdd(&coordsum[cur * 3 + ax], run);
    }

    // msum: two phases of 64 edges; all 256 threads (col x row-half), serial length 32
#pragma unroll
    for (int ph = 0; ph < 2; ++ph) {
        int lr = w * 16 + m_;
#pragma unroll
        for (int ot = 0; ot < 8; ++ot)
            *(f32x4_t*)(Mf + lr * 132 + ot * 16 + q * 4) = acc[ph][ot];
        __syncthreads();   // Mf complete
        {
            int c = t & 127;
            int half = t >> 7;               // wave-uniform (waves 0,1 -> 0; 2,3 -> 1)
            int base = ph * 64 + half * 32;
            float run = 0.f;
            int cur = s_dst[base];
            for (int r = 0; r < 32; ++r) {
                int d = s_dst[base + r];     // wave-uniform branch
                if (d != cur) {
                    atomicAdd(&msum[(long)cur * 128 + c], run);
                    run = 0.f; cur = d;
                }
                run += Mf[(half * 32 + r) * 132 + c];
            }
            atomicAdd(&msum[(long)cur * 128 + c], run);
        }
        __syncthreads();   // reduce done before Mf overwrite / exit
    }
}

// ---------------- node kernel: normalize agg + 2-layer node MLP + pos update ----------------
__global__ __launch_bounds__(256, 2)
void node_kernel(const __bf16* __restrict__ xb,
                 const float* __restrict__ msum,
                 const int* __restrict__ off,
                 const __bf16* __restrict__ Wn1T,
                 const float* __restrict__ bn1,
                 const __bf16* __restrict__ Wn2T,
                 const float* __restrict__ bn2,
                 const float* __restrict__ pos,
                 const float* __restrict__ csum,
                 float* __restrict__ xout,
                 float* __restrict__ pout) {
    __shared__ __align__(16) __bf16 Abf[64 * 264];
    __shared__ __align__(16) __bf16 Wt[128 * 56];
    __shared__ __align__(16) __bf16 A2[64 * 136];

    const int t = threadIdx.x;
    const int r0 = blockIdx.x * 64;
    const int w = t >> 6;
    const int lane = t & 63;
    const int m_ = lane & 15;
    const int q = lane >> 4;

    // pos update for this block's 64 nodes (independent of the MLP)
    if (t < 192) {
        int node = r0 + t / 3;
        if (node < NN) {
            int dg = off[node + 1] - off[node];
            float inv = 1.f / (float)(dg < 1 ? 1 : dg);
            int fl = node * 3 + t % 3;
            pout[fl] = pos[fl] + csum[fl] * inv;
        }
    }

    for (int i = 0; i < 8; ++i) {
        int id = t + 256 * i;
        int rl = id >> 5, ch = id & 31;
        int row = r0 + rl;
        int c8 = (ch & 15) * 8;
        union { __bf16 h[8]; uint4 u; } pk;
        if (row < NN) {
            if (ch < 16) {
                pk.u = *(const uint4*)(xb + (long)row * 128 + c8);
            } else {
                const float* mp = msum + (long)row * 128 + c8;
                int dg = off[row + 1] - off[row];
                float inv = 1.f / (float)(dg < 1 ? 1 : dg);
#pragma unroll
                for (int j = 0; j < 8; ++j) pk.h[j] = (__bf16)(mp[j] * inv);
            }
        } else {
            pk.u = make_uint4(0, 0, 0, 0);
        }
        *(uint4*)(Abf + rl * 264 + ((ch < 16) ? 0 : 128) + c8) = pk.u;
    }
    __syncthreads();

    f32x4_t acc[8];
#pragma unroll
    for (int ct = 0; ct < 8; ++ct) acc[ct] = (f32x4_t){0.f, 0.f, 0.f, 0.f};

    for (int ks = 0; ks < 8; ++ks) {
#pragma unroll
        for (int i = 0; i < 2; ++i) {
            int c = t + 256 * i;
            int n = c >> 2, ko = (c & 3) * 8;
            uint4 v = *(const uint4*)(Wn1T + n * 256 + ks * 32 + ko);
            *(uint4*)(Wt + n * 56 + ko) = v;
        }
        __syncthreads();
        bf16x8_t a = *(const bf16x8_t*)(Abf + (w * 16 + m_) * 264 + ks * 32 + q * 8);
#pragma unroll
        for (int ct = 0; ct < 8; ++ct) {
            bf16x8_t b = *(const bf16x8_t*)(Wt + (ct * 16 + m_) * 56 + q * 8);
            acc[ct] = __builtin_amdgcn_mfma_f32_16x16x32_bf16(a, b, acc[ct], 0, 0, 0);
        }
        __syncthreads();
    }
#pragma unroll
    for (int ct = 0; ct < 8; ++ct) {
        int c = ct * 16 + m_;
        float b1 = bn1[c];
#pragma unroll
        for (int r = 0; r < 4; ++r) {
            int el = w * 16 + q * 4 + r;
            float v = acc[ct][r] + b1;
            A2[el * 136 + c] = (__bf16)silu_f(v);
        }
    }
    __syncthreads();

#pragma unroll
    for (int ct = 0; ct < 8; ++ct) acc[ct] = (f32x4_t){0.f, 0.f, 0.f, 0.f};

    for (int ks = 0; ks < 4; ++ks) {
#pragma unroll
        for (int i = 0; i < 2; ++i) {
            int c = t + 256 * i;
            int n = c >> 2, ko = (c & 3) * 8;
            uint4 v = *(const uint4*)(Wn2T + n * 128 + ks * 32 + ko);
            *(uint4*)(Wt + n * 56 + ko) = v;
        }
        __syncthreads();
        bf16x8_t a = *(const bf16x8_t*)(A2 + (w * 16 + m_) * 136 + ks * 32 + q * 8);
#pragma unroll
        for (int ct = 0; ct < 8; ++ct) {
            bf16x8_t b = *(const bf16x8_t*)(Wt + (ct * 16 + m_) * 56 + q * 8);
            acc[ct] = __builtin_amdgcn_mfma_f32_16x16x32_bf16(a, b, acc[ct], 0, 0, 0);
        }
        __syncthreads();
    }
#pragma unroll
    for (int ct = 0; ct < 8; ++ct) {
        int c = ct * 16 + m_;
        float b2 = bn2[c];
#pragma unroll
        for (int r = 0; r < 4; ++r) {
            int el = w * 16 + q * 4 + r;
            int row = r0 + el;
            if (row < NN) xout[(long)row * 128 + c] = acc[ct][r] + b2;
        }
    }
}

extern "C" void kernel_launch(void* const* d_in, const int* in_sizes, int n_in,
                              void* d_out, int out_size, void* d_ws, size_t ws_size,
                              hipStream_t stream) {
    const float* x     = (const float*)d_in[0];
    const float* pos   = (const float*)d_in[1];
    const int*   eidx  = (const int*)d_in[2];
    const float* eattr = (const float*)d_in[3];
    const float* s     = (const float*)d_in[4];
    const float* We1   = (const float*)d_in[5];
    const float* be1   = (const float*)d_in[6];
    const float* We2   = (const float*)d_in[7];
    const float* be2   = (const float*)d_in[8];
    const float* Wn1   = (const float*)d_in[9];
    const float* bn1   = (const float*)d_in[10];
    const float* Wn2   = (const float*)d_in[11];
    const float* bn2   = (const float*)d_in[12];
    const float* Wc    = (const float*)d_in[13];
    const float* bc    = (const float*)d_in[14];

    char* ws = (char*)d_ws;
    __bf16* xb     = (__bf16*)(ws);                 // 12,800,000
    __bf16* WyS    = (__bf16*)(ws + 12800000);      //     65,536
    __bf16* We2S   = (__bf16*)(ws + 12865536);      //     32,768
    __bf16* Wn1T   = (__bf16*)(ws + 12898304);      //     65,536
    __bf16* Wn2T   = (__bf16*)(ws + 12963840);      //     32,768
    float*  msum   = (float*)(ws + 12996608);       // 25,600,000
    float*  csum   = (float*)(ws + 38596608);       //    600,000
    int*    hist   = (int*)(ws + 39196608);         //    200,000
    int*    off    = (int*)(ws + 39396608);         //    200,064
    int*    cursor = (int*)(ws + 39596672);         //    200,064
    float4* e_geo  = (float4*)(ws + 39796736);      // 12,800,000 (16B aligned)
    int2*   e_nodes= (int2*)(ws + 52596736);        //  6,400,000
    float2* e_gate = (float2*)(ws + 58996736);      //  6,400,000
    int*    bsum   = (int*)(ws + 65396736);         //      1,024
    __bf16* ya     = (__bf16*)(ws + 65397760);      // 12,800,000
    __bf16* yb     = (__bf16*)(ws + 78197760);      // 12,800,000 (end 90,997,760)

    float* xout = (float*)d_out;
    float* pout = xout + (size_t)NN * 128;

    // zero msum + csum + hist (contiguous, 26.4 MB)
    hipMemsetAsync(ws + 12996608, 0, 26400000, stream);
    prep_kernel<<<1024, 256, 0, stream>>>(x, We1, We2, Wn1, Wn2, eidx,
                                          xb, WyS, We2S, Wn1T, Wn2T, hist);
    ygemm_kernel<<<(NN + 63) / 64, 256, 0, stream>>>(xb, WyS, ya, yb);
    scan_a<<<SCAN_BLOCKS, 256, 0, stream>>>(hist, bsum);
    scan_b<<<1, 256, 0, stream>>>(bsum);
    scan_c<<<SCAN_BLOCKS, 256, 0, stream>>>(hist, bsum, off, cursor);
    scatter_kernel<<<(EE + 255) / 256, 256, 0, stream>>>(eidx, pos, eattr, s, cursor,
                                                         e_geo, e_nodes, e_gate);
    edge_kernel<<<EE / 128, 256, 0, stream>>>(ya, yb, e_geo, e_nodes, e_gate,
                                              We1, be1, We2S, be2, Wc, bc,
                                              msum, csum);
    node_kernel<<<(NN + 63) / 64, 256, 0, stream>>>(xb, msum, off, Wn1T, bn1, Wn2T, bn2,
                                                    pos, csum, xout, pout);
}

// Round 5
// 347.064 us; speedup vs baseline: 1.1875x; 1.0711x over previous
//
#include <hip/hip_runtime.h>
#include <hip/hip_bf16.h>

#define NN 50000
#define EE 800000
#define SCAN_BLOCKS 196   // 196*256 = 50176 >= NN

typedef __bf16 bf16x8_t __attribute__((ext_vector_type(8)));
typedef float f32x4_t __attribute__((ext_vector_type(4)));

__device__ __forceinline__ float silu_f(float v) {
    // v * 1/(1+exp(-v)) with v_rcp_f32 (avoids the ~9-instr precise-div sequence)
    return v * __builtin_amdgcn_rcpf(1.0f + __expf(-v));
}

__device__ __forceinline__ float bf_lo(unsigned u) { return __uint_as_float(u << 16); }
__device__ __forceinline__ float bf_hi(unsigned u) { return __uint_as_float(u & 0xffff0000u); }

// ---------------- prep: x -> bf16, weights -> k-slice-major bf16, dst histogram ----------------
// WyS layout: [ks(4)][h(256)][chunk(32)] bf16 for the per-node y GEMM:
//   h<128 -> y_a (x[dst] part, We1 rows 0..127), h>=128 -> y_b (x[src] part, rows 128..255)
// We2S/Wn2S layout: [ks(4)][row(128)][chunk(32)] bf16; Wn1S: [ks(8)][row(128)][chunk(32)]
__global__ void prep_kernel(const float* __restrict__ x,
                            const float* __restrict__ We1,
                            const float* __restrict__ We2,
                            const float* __restrict__ Wn1,
                            const float* __restrict__ Wn2,
                            const int* __restrict__ eidx,
                            __bf16* __restrict__ xb,
                            __bf16* __restrict__ WyS,
                            __bf16* __restrict__ We2S,
                            __bf16* __restrict__ Wn1S,
                            __bf16* __restrict__ Wn2S,
                            int* __restrict__ hist) {
    int tid = blockIdx.x * blockDim.x + threadIdx.x;
    int np = gridDim.x * blockDim.x;
    const int NX = NN * 128 / 4;
    for (int i = tid; i < NX; i += np) {
        float4 v = ((const float4*)x)[i];
        __bf16* o = xb + (size_t)i * 4;
        o[0] = (__bf16)v.x; o[1] = (__bf16)v.y; o[2] = (__bf16)v.z; o[3] = (__bf16)v.w;
    }
    for (int i = tid; i < 256 * 128; i += np) {
        int k = i >> 7, n = i & 127;
        int h = (k < 128) ? n : (128 + n);
        int k2 = k & 127;
        WyS[(k2 >> 5) * 8192 + h * 32 + (k2 & 31)] = (__bf16)We1[i];
        Wn1S[(k >> 5) * 4096 + n * 32 + (k & 31)] = (__bf16)Wn1[i];
    }
    for (int i = tid; i < 128 * 128; i += np) {
        int k = i >> 7, n = i & 127;
        We2S[(k >> 5) * 4096 + n * 32 + (k & 31)] = (__bf16)We2[i];
        Wn2S[(k >> 5) * 4096 + n * 32 + (k & 31)] = (__bf16)Wn2[i];
    }
    for (int i = tid; i < EE; i += np) {
        atomicAdd(&hist[eidx[EE + i]], 1);
    }
}

// ---------------- per-node y GEMM v2: operand-swapped, bf16 split output, no x staging ----------------
__global__ __launch_bounds__(256, 3)
void ygemm_kernel(const __bf16* __restrict__ xb,
                  const __bf16* __restrict__ WyS,
                  __bf16* __restrict__ ya,
                  __bf16* __restrict__ yb) {
    __shared__ __align__(16) __bf16 Wy[256 * 32];   // 16 KB, XOR-swizzled chunks

    const int t = threadIdx.x;
    const int r0 = blockIdx.x * 64;
    const int w = t >> 6;
    const int lane = t & 63;
    const int m_ = lane & 15;
    const int q = lane >> 4;

    const int node = r0 + w * 16 + m_;
    const long nrow = (long)(node < NN ? node : NN - 1) * 128;

    f32x4_t acc[16];
#pragma unroll
    for (int ot = 0; ot < 16; ++ot) acc[ot] = (f32x4_t){0.f, 0.f, 0.f, 0.f};

    const int wrow = t >> 2;                        // 0..63
    const int pch = (t & 3) ^ ((wrow >> 1) & 3);
    const int wofs = wrow * 32 + pch * 8;
    const int rofs = m_ * 32 + (q ^ ((m_ >> 1) & 3)) * 8;

    bf16x8_t xf = *(const bf16x8_t*)(xb + nrow + q * 8);
    uint4 v0 = *(const uint4*)(WyS + t * 8);
    uint4 v1 = *(const uint4*)(WyS + 2048 + t * 8);
    uint4 v2 = *(const uint4*)(WyS + 4096 + t * 8);
    uint4 v3 = *(const uint4*)(WyS + 6144 + t * 8);
#pragma unroll
    for (int ks = 0; ks < 4; ++ks) {
        __syncthreads();                 // prior Wy reads done
        *(uint4*)(Wy + wofs) = v0;
        *(uint4*)(Wy + 64 * 32 + wofs) = v1;
        *(uint4*)(Wy + 128 * 32 + wofs) = v2;
        *(uint4*)(Wy + 192 * 32 + wofs) = v3;
        __syncthreads();                 // Wy ready
        bf16x8_t nxf;
        if (ks < 3) {                    // prefetch during MFMA phase
            v0 = *(const uint4*)(WyS + (ks + 1) * 8192 + t * 8);
            v1 = *(const uint4*)(WyS + (ks + 1) * 8192 + 2048 + t * 8);
            v2 = *(const uint4*)(WyS + (ks + 1) * 8192 + 4096 + t * 8);
            v3 = *(const uint4*)(WyS + (ks + 1) * 8192 + 6144 + t * 8);
            nxf = *(const bf16x8_t*)(xb + nrow + (ks + 1) * 32 + q * 8);
        }
#pragma unroll
        for (int ot = 0; ot < 16; ++ot) {
            bf16x8_t wf = *(const bf16x8_t*)(Wy + ot * (16 * 32) + rofs);
            acc[ot] = __builtin_amdgcn_mfma_f32_16x16x32_bf16(wf, xf, acc[ot], 0, 0, 0);
        }
        if (ks < 3) xf = nxf;
    }

    if (node < NN) {
#pragma unroll
        for (int ot = 0; ot < 16; ++ot) {
            union { __bf16 h[4]; uint2 u; } pk;
            pk.h[0] = (__bf16)acc[ot][0];
            pk.h[1] = (__bf16)acc[ot][1];
            pk.h[2] = (__bf16)acc[ot][2];
            pk.h[3] = (__bf16)acc[ot][3];
            int col = (ot & 7) * 16 + q * 4;
            __bf16* dst = (ot < 8 ? ya : yb) + (long)node * 128 + col;
            *(uint2*)dst = pk.u;
        }
    }
}

// ---------------- counting-sort scan (3 tiny kernels) ----------------
__global__ void scan_a(const int* __restrict__ hist, int* __restrict__ bsum) {
    __shared__ int sh[256];
    int i = blockIdx.x * 256 + threadIdx.x;
    sh[threadIdx.x] = (i < NN) ? hist[i] : 0;
    __syncthreads();
    for (int s = 128; s > 0; s >>= 1) {
        if (threadIdx.x < s) sh[threadIdx.x] += sh[threadIdx.x + s];
        __syncthreads();
    }
    if (threadIdx.x == 0) bsum[blockIdx.x] = sh[0];
}

__global__ void scan_b(int* __restrict__ bsum) {
    __shared__ int sh[SCAN_BLOCKS];
    int t = threadIdx.x;
    if (t < SCAN_BLOCKS) sh[t] = bsum[t];
    __syncthreads();
    if (t == 0) {
        int acc = 0;
        for (int i = 0; i < SCAN_BLOCKS; ++i) { int v = sh[i]; sh[i] = acc; acc += v; }
    }
    __syncthreads();
    if (t < SCAN_BLOCKS) bsum[t] = sh[t];
}

__global__ void scan_c(const int* __restrict__ hist, const int* __restrict__ bsum,
                       int* __restrict__ off, int* __restrict__ cursor) {
    __shared__ int sh[256];
    int tx = threadIdx.x;
    int i = blockIdx.x * 256 + tx;
    int v = (i < NN) ? hist[i] : 0;
    sh[tx] = v;
    __syncthreads();
    for (int s = 1; s < 256; s <<= 1) {
        int add = (tx >= s) ? sh[tx - s] : 0;
        __syncthreads();
        sh[tx] += add;
        __syncthreads();
    }
    int excl = sh[tx] - v + bsum[blockIdx.x];
    if (i < NN) { off[i] = excl; cursor[i] = excl; }
    if (i == NN - 1) off[NN] = excl + v;
}

// ---------------- scatter: build sorted 32B per-edge records (1 cache line per edge) ----------------
// erec[p] = {dx,dy,dz,r2 | si,di,ea,sg} as two adjacent uint4 (always one 64B line).
__global__ void scatter_kernel(const int* __restrict__ eidx,
                               const float* __restrict__ pos,
                               const float* __restrict__ eattr,
                               const float* __restrict__ s,
                               int* __restrict__ cursor,
                               uint4* __restrict__ erec) {
    int i = blockIdx.x * blockDim.x + threadIdx.x;
    if (i < EE) {
        int si = eidx[i];
        int di = eidx[EE + i];
        int p = atomicAdd(&cursor[di], 1);
        float dx = pos[di * 3 + 0] - pos[si * 3 + 0];
        float dy = pos[di * 3 + 1] - pos[si * 3 + 1];
        float dz = pos[di * 3 + 2] - pos[si * 3 + 2];
        float r2 = dx * dx + dy * dy + dz * dz;
        uint4 a = make_uint4(__float_as_uint(dx), __float_as_uint(dy),
                             __float_as_uint(dz), __float_as_uint(r2));
        uint4 b = make_uint4((unsigned)si, (unsigned)di,
                             __float_as_uint(eattr[i]), __float_as_uint(s[si]));
        erec[(size_t)p * 2] = a;
        erec[(size_t)p * 2 + 1] = b;
    }
}

// ---------------- edge kernel v9: 32B records; phase-1 depth-2 gather pipeline ----------------
__global__ __launch_bounds__(256, 3)
void edge_kernel(const __bf16* __restrict__ ya,
                 const __bf16* __restrict__ yb,
                 const uint4* __restrict__ erec,
                 const float* __restrict__ We1,   // f32, rows 256/257 (r2, edge_attr)
                 const float* __restrict__ be1,
                 const __bf16* __restrict__ We2S,
                 const float* __restrict__ be2,
                 const float* __restrict__ Wc,
                 const float* __restrict__ bc,
                 float* __restrict__ msum,
                 float* __restrict__ coordsum) {
    __shared__ __align__(16) __bf16 Wt[128 * 32];   //  8,192 B
    __shared__ __align__(16) __bf16 A2[128 * 136];  // 34,816 B; Mf (f32 64x132) aliases
    __shared__ __align__(16) float4 s_pk[128];      //  2,048 B {r2, ea, src, dst}
    __shared__ float s_sg[128], s_g[128];
    __shared__ float s_diff[128 * 3];
    __shared__ int s_dst[128];

    float* Mf = (float*)A2;

    const int t = threadIdx.x;
    const int e0 = blockIdx.x * 128;
    const int w = t >> 6;
    const int lane = t & 63;
    const int m_ = lane & 15;
    const int q = lane >> 4;

    // per-edge scalars: one 32B record per edge, coalesced
    if (t < 128) {
        const uint4* er = erec + (size_t)(e0 + t) * 2;
        uint4 a = er[0];
        uint4 b = er[1];
        s_diff[t * 3 + 0] = __uint_as_float(a.x);
        s_diff[t * 3 + 1] = __uint_as_float(a.y);
        s_diff[t * 3 + 2] = __uint_as_float(a.z);
        s_pk[t] = make_float4(__uint_as_float(a.w), __uint_as_float(b.z),
                              __uint_as_float(b.x), __uint_as_float(b.y));
        s_sg[t] = __uint_as_float(b.w);
        s_dst[t] = (int)b.y;
    }
    __syncthreads();

    const int el0 = w * 16 + m_;
    const int el1 = 64 + w * 16 + m_;

    // ---- phase 1: element-wise layer 1, depth-2 pipelined gathers ----
    {
        const int c8 = (t & 15) * 8;     // 8-col chunk
        const int eb = t >> 4;           // 0..15
        float4 b1a = *(const float4*)(be1 + c8);
        float4 b1b = *(const float4*)(be1 + c8 + 4);
        float4 w6a = *(const float4*)(We1 + 256 * 128 + c8);
        float4 w6b = *(const float4*)(We1 + 256 * 128 + c8 + 4);
        float4 w7a = *(const float4*)(We1 + 257 * 128 + c8);
        float4 w7b = *(const float4*)(We1 + 257 * 128 + c8 + 4);
        float4 pk4 = s_pk[eb];
        uint4 av = *(const uint4*)(ya + (long)__float_as_int(pk4.w) * 128 + c8);
        uint4 bv = *(const uint4*)(yb + (long)__float_as_int(pk4.z) * 128 + c8);
#pragma unroll
        for (int i = 0; i < 8; ++i) {
            float4 pk4n; uint4 avn, bvn;
            if (i < 7) {                 // issue next gathers before this iter's VALU
                pk4n = s_pk[eb + (i + 1) * 16];
                avn = *(const uint4*)(ya + (long)__float_as_int(pk4n.w) * 128 + c8);
                bvn = *(const uint4*)(yb + (long)__float_as_int(pk4n.z) * 128 + c8);
            }
            int e = eb + i * 16;
            float r2 = pk4.x, ea = pk4.y;
            union { __bf16 h[8]; uint4 u; } pk;
            pk.h[0] = (__bf16)silu_f(bf_lo(av.x) + bf_lo(bv.x) + b1a.x + r2 * w6a.x + ea * w7a.x);
            pk.h[1] = (__bf16)silu_f(bf_hi(av.x) + bf_hi(bv.x) + b1a.y + r2 * w6a.y + ea * w7a.y);
            pk.h[2] = (__bf16)silu_f(bf_lo(av.y) + bf_lo(bv.y) + b1a.z + r2 * w6a.z + ea * w7a.z);
            pk.h[3] = (__bf16)silu_f(bf_hi(av.y) + bf_hi(bv.y) + b1a.w + r2 * w6a.w + ea * w7a.w);
            pk.h[4] = (__bf16)silu_f(bf_lo(av.z) + bf_lo(bv.z) + b1b.x + r2 * w6b.x + ea * w7b.x);
            pk.h[5] = (__bf16)silu_f(bf_hi(av.z) + bf_hi(bv.z) + b1b.y + r2 * w6b.y + ea * w7b.y);
            pk.h[6] = (__bf16)silu_f(bf_lo(av.w) + bf_lo(bv.w) + b1b.z + r2 * w6b.z + ea * w7b.z);
            pk.h[7] = (__bf16)silu_f(bf_hi(av.w) + bf_hi(bv.w) + b1b.w + r2 * w6b.w + ea * w7b.w);
            *(uint4*)(A2 + e * 136 + c8) = pk.u;
            if (i < 7) { pk4 = pk4n; av = avn; bv = bvn; }
        }
    }

    f32x4_t acc[2][8];
#pragma unroll
    for (int et = 0; et < 2; ++et)
#pragma unroll
        for (int ot = 0; ot < 8; ++ot) acc[et][ot] = (f32x4_t){0.f, 0.f, 0.f, 0.f};

    // staging addresses (XOR-swizzled, coalesced; see r2 notes)
    const int wrow = t >> 2;
    const int pch = (t & 3) ^ ((wrow >> 1) & 3);
    const int wofs = wrow * 32 + pch * 8;
    const int rofs = m_ * 32 + (q ^ ((m_ >> 1) & 3)) * 8;

    // ---- phase 2: layer 2, K = 128, B-operand = A2 rows (same-wave LDS) ----
    uint4 w20 = *(const uint4*)(We2S + t * 8);
    uint4 w21 = *(const uint4*)(We2S + 2048 + t * 8);
#pragma unroll
    for (int ks = 0; ks < 4; ++ks) {
        __syncthreads();                 // A2 writes (ks=0) / prior wf reads; drains prefetch
        *(uint4*)(Wt + wofs) = w20;
        *(uint4*)(Wt + 64 * 32 + wofs) = w21;
        __syncthreads();                 // Wt ready
        if (ks < 3) {                    // prefetch during MFMA phase (drains at next bar1)
            w20 = *(const uint4*)(We2S + (ks + 1) * 4096 + t * 8);
            w21 = *(const uint4*)(We2S + (ks + 1) * 4096 + 2048 + t * 8);
        }
        bf16x8_t af0 = *(const bf16x8_t*)(A2 + el0 * 136 + ks * 32 + q * 8);
        bf16x8_t af1 = *(const bf16x8_t*)(A2 + el1 * 136 + ks * 32 + q * 8);
#pragma unroll
        for (int ot = 0; ot < 8; ++ot) {
            bf16x8_t wf = *(const bf16x8_t*)(Wt + ot * (16 * 32) + rofs);
            acc[0][ot] = __builtin_amdgcn_mfma_f32_16x16x32_bf16(wf, af0, acc[0][ot], 0, 0, 0);
            acc[1][ot] = __builtin_amdgcn_mfma_f32_16x16x32_bf16(wf, af1, acc[1][ot], 0, 0, 0);
        }
    }

    // epilogue 2: + b, SiLU, * s[src]; gamma via q-lane shuffle reduce
    {
        float sg0 = s_sg[el0], sg1 = s_sg[el1];
        float gp0 = 0.f, gp1 = 0.f;
#pragma unroll
        for (int ot = 0; ot < 8; ++ot) {
            int oc = ot * 16 + q * 4;
            float4 b2 = *(const float4*)(be2 + oc);
            float4 wc = *(const float4*)(Wc + oc);
            f32x4_t v0_ = acc[0][ot], v1_ = acc[1][ot];
            v0_[0] = silu_f(v0_[0] + b2.x) * sg0; v0_[1] = silu_f(v0_[1] + b2.y) * sg0;
            v0_[2] = silu_f(v0_[2] + b2.z) * sg0; v0_[3] = silu_f(v0_[3] + b2.w) * sg0;
            v1_[0] = silu_f(v1_[0] + b2.x) * sg1; v1_[1] = silu_f(v1_[1] + b2.y) * sg1;
            v1_[2] = silu_f(v1_[2] + b2.z) * sg1; v1_[3] = silu_f(v1_[3] + b2.w) * sg1;
            acc[0][ot] = v0_; acc[1][ot] = v1_;
            gp0 += v0_[0] * wc.x + v0_[1] * wc.y + v0_[2] * wc.z + v0_[3] * wc.w;
            gp1 += v1_[0] * wc.x + v1_[1] * wc.y + v1_[2] * wc.z + v1_[3] * wc.w;
        }
        gp0 += __shfl_xor(gp0, 16); gp0 += __shfl_xor(gp0, 32);
        gp1 += __shfl_xor(gp1, 16); gp1 += __shfl_xor(gp1, 32);
        if (q == 0) {
            float b0 = bc[0];
            s_g[el0] = gp0 + b0;
            s_g[el1] = gp1 + b0;
        }
    }
    __syncthreads();   // P0: all A2 reads done (Mf aliases), s_g visible

    // coord: 24 threads, 3 axes x 8 row-chunks of 16 (atomics make chunk splits safe)
    if (t < 24) {
        int ax = t % 3, ch = t / 3;
        int base = ch * 16;
        float run = 0.f;
        int cur = s_dst[base];
        for (int r = 0; r < 16; ++r) {
            int rr = base + r;
            int d = s_dst[rr];
            if (d != cur) {
                atomicAdd(&coordsum[cur * 3 + ax], run);
                run = 0.f; cur = d;
            }
            run += s_g[rr] * s_diff[rr * 3 + ax];
        }
        atomicAdd(&coordsum[cur * 3 + ax], run);
    }

    // msum: two phases of 64 edges; all 256 threads (col x row-half), serial length 32
#pragma unroll
    for (int ph = 0; ph < 2; ++ph) {
        int lr = w * 16 + m_;
#pragma unroll
        for (int ot = 0; ot < 8; ++ot)
            *(f32x4_t*)(Mf + lr * 132 + ot * 16 + q * 4) = acc[ph][ot];
        __syncthreads();   // Mf complete
        {
            int c = t & 127;
            int half = t >> 7;               // wave-uniform (waves 0,1 -> 0; 2,3 -> 1)
            int base = ph * 64 + half * 32;
            float run = 0.f;
            int cur = s_dst[base];
            for (int r = 0; r < 32; ++r) {
                int d = s_dst[base + r];     // wave-uniform branch
                if (d != cur) {
                    atomicAdd(&msum[(long)cur * 128 + c], run);
                    run = 0.f; cur = d;
                }
                run += Mf[(half * 32 + r) * 132 + c];
            }
            atomicAdd(&msum[(long)cur * 128 + c], run);
        }
        __syncthreads();   // reduce done before Mf overwrite / exit
    }
}

// ---------------- node kernel v2: operand-swapped, no Abf staging, 4 blocks/CU ----------------
// lane(m_,q) of wave w owns node r0 + w*16 + m_; out-cols ot*16+q*4+{0..3}.
// layer 1: K=256 (k<128 from xb, k>=128 from msum*inv); layer 2: K=128 from A2 LDS.
__global__ __launch_bounds__(256, 4)
void node_kernel(const __bf16* __restrict__ xb,
                 const float* __restrict__ msum,
                 const int* __restrict__ off,
                 const __bf16* __restrict__ Wn1S,
                 const float* __restrict__ bn1,
                 const __bf16* __restrict__ Wn2S,
                 const float* __restrict__ bn2,
                 const float* __restrict__ pos,
                 const float* __restrict__ csum,
                 float* __restrict__ xout,
                 float* __restrict__ pout) {
    __shared__ __align__(16) __bf16 Wt[128 * 32];   //  8,192 B
    __shared__ __align__(16) __bf16 A2[64 * 136];   // 17,408 B

    const int t = threadIdx.x;
    const int r0 = blockIdx.x * 64;
    const int w = t >> 6;
    const int lane = t & 63;
    const int m_ = lane & 15;
    const int q = lane >> 4;

    // pos update for this block's 64 nodes (independent of the MLP)
    if (t < 192) {
        int node = r0 + t / 3;
        if (node < NN) {
            int dg = off[node + 1] - off[node];
            float inv = 1.f / (float)(dg < 1 ? 1 : dg);
            int fl = node * 3 + t % 3;
            pout[fl] = pos[fl] + csum[fl] * inv;
        }
    }

    const int node = r0 + w * 16 + m_;
    const int ncl = node < NN ? node : NN - 1;
    const long nrow = (long)ncl * 128;
    const int dg = off[ncl + 1] - off[ncl];
    const float inv = 1.f / (float)(dg < 1 ? 1 : dg);

    f32x4_t acc[8];
#pragma unroll
    for (int ot = 0; ot < 8; ++ot) acc[ot] = (f32x4_t){0.f, 0.f, 0.f, 0.f};

    const int wrow = t >> 2;
    const int pch = (t & 3) ^ ((wrow >> 1) & 3);
    const int wofs = wrow * 32 + pch * 8;
    const int rofs = m_ * 32 + (q ^ ((m_ >> 1) & 3)) * 8;

    // ---- layer 1: K = 256; ks<4 from xb (bf16), ks>=4 from msum*inv (f32->bf16) ----
    bf16x8_t xf = *(const bf16x8_t*)(xb + nrow + q * 8);
    float4 mf0, mf1;
    uint4 v0 = *(const uint4*)(Wn1S + t * 8);
    uint4 v1 = *(const uint4*)(Wn1S + 2048 + t * 8);
#pragma unroll
    for (int ks = 0; ks < 8; ++ks) {
        __syncthreads();                 // prior Wt reads done
        *(uint4*)(Wt + wofs) = v0;
        *(uint4*)(Wt + 64 * 32 + wofs) = v1;
        __syncthreads();                 // Wt ready
        bf16x8_t nxf; float4 nm0, nm1;
        if (ks < 7) {                    // prefetch next slice + next input fragment
            v0 = *(const uint4*)(Wn1S + (ks + 1) * 4096 + t * 8);
            v1 = *(const uint4*)(Wn1S + (ks + 1) * 4096 + 2048 + t * 8);
            if (ks + 1 < 4) {
                nxf = *(const bf16x8_t*)(xb + nrow + (ks + 1) * 32 + q * 8);
            } else {
                const float* mp = msum + nrow + (ks + 1 - 4) * 32 + q * 8;
                nm0 = *(const float4*)(mp);
                nm1 = *(const float4*)(mp + 4);
            }
        }
        bf16x8_t cf;
        if (ks < 4) {
            cf = xf;
        } else {
            union { __bf16 h[8]; bf16x8_t v; } u;
            u.h[0] = (__bf16)(mf0.x * inv); u.h[1] = (__bf16)(mf0.y * inv);
            u.h[2] = (__bf16)(mf0.z * inv); u.h[3] = (__bf16)(mf0.w * inv);
            u.h[4] = (__bf16)(mf1.x * inv); u.h[5] = (__bf16)(mf1.y * inv);
            u.h[6] = (__bf16)(mf1.z * inv); u.h[7] = (__bf16)(mf1.w * inv);
            cf = u.v;
        }
#pragma unroll
        for (int ot = 0; ot < 8; ++ot) {
            bf16x8_t wf = *(const bf16x8_t*)(Wt + ot * (16 * 32) + rofs);
            acc[ot] = __builtin_amdgcn_mfma_f32_16x16x32_bf16(wf, cf, acc[ot], 0, 0, 0);
        }
        if (ks < 7) {
            if (ks + 1 < 4) xf = nxf;
            else { mf0 = nm0; mf1 = nm1; }
        }
    }

    // epilogue 1: + bn1, SiLU -> A2 (same-wave rows)
#pragma unroll
    for (int ot = 0; ot < 8; ++ot) {
        float4 b1 = *(const float4*)(bn1 + ot * 16 + q * 4);
        union { __bf16 h[4]; uint2 u; } pk;
        pk.h[0] = (__bf16)silu_f(acc[ot][0] + b1.x);
        pk.h[1] = (__bf16)silu_f(acc[ot][1] + b1.y);
        pk.h[2] = (__bf16)silu_f(acc[ot][2] + b1.z);
        pk.h[3] = (__bf16)silu_f(acc[ot][3] + b1.w);
        *(uint2*)(A2 + (w * 16 + m_) * 136 + ot * 16 + q * 4) = pk.u;
        acc[ot] = (f32x4_t){0.f, 0.f, 0.f, 0.f};
    }

    // ---- layer 2: K = 128, B-operand = A2 row fragments (same-wave LDS) ----
    uint4 u0 = *(const uint4*)(Wn2S + t * 8);
    uint4 u1 = *(const uint4*)(Wn2S + 2048 + t * 8);
#pragma unroll
    for (int ks = 0; ks < 4; ++ks) {
        __syncthreads();                 // prior Wt reads done
        *(uint4*)(Wt + wofs) = u0;
        *(uint4*)(Wt + 64 * 32 + wofs) = u1;
        __syncthreads();                 // Wt ready
        if (ks < 3) {
            u0 = *(const uint4*)(Wn2S + (ks + 1) * 4096 + t * 8);
            u1 = *(const uint4*)(Wn2S + (ks + 1) * 4096 + 2048 + t * 8);
        }
        bf16x8_t af = *(const bf16x8_t*)(A2 + (w * 16 + m_) * 136 + ks * 32 + q * 8);
#pragma unroll
        for (int ot = 0; ot < 8; ++ot) {
            bf16x8_t wf = *(const bf16x8_t*)(Wt + ot * (16 * 32) + rofs);
            acc[ot] = __builtin_amdgcn_mfma_f32_16x16x32_bf16(wf, af, acc[ot], 0, 0, 0);
        }
    }

    // epilogue 2: + bn2, coalesced float4 stores
    if (node < NN) {
#pragma unroll
        for (int ot = 0; ot < 8; ++ot) {
            float4 b2 = *(const float4*)(bn2 + ot * 16 + q * 4);
            float4 o;
            o.x = acc[ot][0] + b2.x; o.y = acc[ot][1] + b2.y;
            o.z = acc[ot][2] + b2.z; o.w = acc[ot][3] + b2.w;
            *(float4*)(xout + nrow + ot * 16 + q * 4) = o;
        }
    }
}

extern "C" void kernel_launch(void* const* d_in, const int* in_sizes, int n_in,
                              void* d_out, int out_size, void* d_ws, size_t ws_size,
                              hipStream_t stream) {
    const float* x     = (const float*)d_in[0];
    const float* pos   = (const float*)d_in[1];
    const int*   eidx  = (const int*)d_in[2];
    const float* eattr = (const float*)d_in[3];
    const float* s     = (const float*)d_in[4];
    const float* We1   = (const float*)d_in[5];
    const float* be1   = (const float*)d_in[6];
    const float* We2   = (const float*)d_in[7];
    const float* be2   = (const float*)d_in[8];
    const float* Wn1   = (const float*)d_in[9];
    const float* bn1   = (const float*)d_in[10];
    const float* Wn2   = (const float*)d_in[11];
    const float* bn2   = (const float*)d_in[12];
    const float* Wc    = (const float*)d_in[13];
    const float* bc    = (const float*)d_in[14];

    char* ws = (char*)d_ws;
    __bf16* xb     = (__bf16*)(ws);                 // 12,800,000
    __bf16* WyS    = (__bf16*)(ws + 12800000);      //     65,536
    __bf16* We2S   = (__bf16*)(ws + 12865536);      //     32,768
    __bf16* Wn1S   = (__bf16*)(ws + 12898304);      //     65,536
    __bf16* Wn2S   = (__bf16*)(ws + 12963840);      //     32,768
    float*  msum   = (float*)(ws + 12996608);       // 25,600,000
    float*  csum   = (float*)(ws + 38596608);       //    600,000
    int*    hist   = (int*)(ws + 39196608);         //    200,000
    int*    off    = (int*)(ws + 39396608);         //    200,064
    int*    cursor = (int*)(ws + 39596672);         //    200,064
    uint4*  erec   = (uint4*)(ws + 39796736);       // 25,600,000 (32B/edge)
    int*    bsum   = (int*)(ws + 65396736);         //      1,024
    __bf16* ya     = (__bf16*)(ws + 65397760);      // 12,800,000
    __bf16* yb     = (__bf16*)(ws + 78197760);      // 12,800,000 (end 90,997,760)

    float* xout = (float*)d_out;
    float* pout = xout + (size_t)NN * 128;

    // zero msum + csum + hist (contiguous, 26.4 MB)
    hipMemsetAsync(ws + 12996608, 0, 26400000, stream);
    prep_kernel<<<1024, 256, 0, stream>>>(x, We1, We2, Wn1, Wn2, eidx,
                                          xb, WyS, We2S, Wn1S, Wn2S, hist);
    ygemm_kernel<<<(NN + 63) / 64, 256, 0, stream>>>(xb, WyS, ya, yb);
    scan_a<<<SCAN_BLOCKS, 256, 0, stream>>>(hist, bsum);
    scan_b<<<1, 256, 0, stream>>>(bsum);
    scan_c<<<SCAN_BLOCKS, 256, 0, stream>>>(hist, bsum, off, cursor);
    scatter_kernel<<<(EE + 255) / 256, 256, 0, stream>>>(eidx, pos, eattr, s, cursor, erec);
    edge_kernel<<<EE / 128, 256, 0, stream>>>(ya, yb, erec,
                                              We1, be1, We2S, be2, Wc, bc,
                                              msum, csum);
    node_kernel<<<(NN + 63) / 64, 256, 0, stream>>>(xb, msum, off, Wn1S, bn1, Wn2S, bn2,
                                                    pos, csum, xout, pout);
}